// Round 14
// baseline (26.310 us; speedup 1.0000x reference)
//
#include <hip/hip_runtime.h>
#include <math.h>

#define D 128
#define NPARAMS 16
#define H 256
#define XCOLS (D + NPARAMS)   // 144
#define BATCH 4096
#define NTOT (BATCH * D)      // 524288

#define INV_2PI_F 0.15915494309189535f
#define OUT_SCALE 2.5132741228718345f   // 2*pi / 2.5

typedef __attribute__((ext_vector_type(8))) short short8;   // 8 bf16 (4 VGPR)
typedef __attribute__((ext_vector_type(4))) float f32x4;    // MFMA acc

__device__ __forceinline__ unsigned rne16(float x) {        // fp32 -> bf16 RNE
    unsigned u = __float_as_uint(x);
    return (u + 0x7fffu + ((u >> 16) & 1u)) >> 16;
}

// ---------------- weight pre-pack into MFMA B-fragments (bf16) ---------------
// B-frag slot (ntile t, kstep s, lane l): B[k][j] = W[j][k],
// j = 16t + (l&15), k = 32s + (l>>4)*8 + e.

__global__ __launch_bounds__(256) void pack_kernel(
    const float* __restrict__ w_in, const float* __restrict__ w0,
    const float* __restrict__ w1,   const float* __restrict__ w_out,
    short8* __restrict__ pw_in, short8* __restrict__ pwb0,
    short8* __restrict__ pwb1,  short8* __restrict__ pwb2)
{
    int tid = blockIdx.x * 256 + threadIdx.x;
    if (tid < 24576) {                      // 3 matrices x 8192 slots
        const float* W = (tid < 8192) ? w0 : (tid < 16384) ? w1 : w_out;
        short8* P      = (tid < 8192) ? pwb0 : (tid < 16384) ? pwb1 : pwb2;
        int slot = tid & 8191;
        int l = slot & 63, ts = slot >> 6;
        int s = ts & 7, t = ts >> 3;
        int j = 16 * t + (l & 15);
        int kb = 32 * s + ((l >> 4) << 3);
        const float* src = W + j * H + kb;
        short8 v;
        #pragma unroll
        for (int e = 0; e < 8; ++e) v[e] = (short)rne16(src[e]);
        P[slot] = v;
    } else if (tid < 25600) {               // input layer: 1024 slots, K=16 pad
        int slot = tid - 24576;
        int l = slot & 63, t = slot >> 6;
        int j = 16 * t + (l & 15), gg = l >> 4;
        short8 v = {0, 0, 0, 0, 0, 0, 0, 0};
        if (gg < 2) {
            const float* src = w_in + j * NPARAMS + gg * 8;
            #pragma unroll
            for (int e = 0; e < 8; ++e) v[e] = (short)rne16(src[e]);
        }
        pw_in[slot] = v;
    }
}

// ---------------- MFMA MLP, occupancy-first ----------------------------------
// Grid 512 x 512 thr (8 waves), 8 REAL samples/block (A rows 8..15 are
// don't-care: MFMA rows are independent, garbage never contaminates real
// rows and is never stored). __launch_bounds__(512,4) caps VGPR <= 128 ->
// 2 blocks/CU = 4 waves/SIMD: two independent barrier domains overlap.

__device__ __forceinline__ int act_addr(int row, int colbyte) {
    return (row * 512 + colbyte) ^ ((row & 7) << 4);
}

__device__ __forceinline__ short8 load_afrag16(const char* actb, int li, int g, int s) {
    return *reinterpret_cast<const short8*>(actb + act_addr(li, s * 64 + g * 16));
}

__device__ __forceinline__ void store_act16(char* actb, const f32x4 acc[2],
                                            int li, int g, int w, bool relu) {
    #pragma unroll
    for (int t = 0; t < 2; ++t) {
        int col = (2 * w + t) * 16 + li;
        #pragma unroll
        for (int r = 0; r < 4; ++r) {
            int row = g * 4 + r;
            float v = relu ? fmaxf(acc[t][r], 0.f) : acc[t][r];
            *reinterpret_cast<short*>(actb + act_addr(row, col * 2)) = (short)rne16(v);
        }
    }
}

__device__ __forceinline__ void hidden_layer16(
    const char* actb, const short8* __restrict__ pwb,
    const float* __restrict__ bias, int lane, int li, int g, int w,
    f32x4 acc[2])
{
    short8 af[8];
    #pragma unroll
    for (int s = 0; s < 8; ++s) af[s] = load_afrag16(actb, li, g, s);

    #pragma unroll
    for (int t = 0; t < 2; ++t) {
        short8 bf[8];
        #pragma unroll
        for (int s = 0; s < 8; ++s)
            bf[s] = pwb[((2 * w + t) * 8 + s) * 64 + lane];
        float bb = bias[(2 * w + t) * 16 + li];
        f32x4 a = {bb, bb, bb, bb};
        #pragma unroll
        for (int s = 0; s < 8; ++s)
            a = __builtin_amdgcn_mfma_f32_16x16x32_bf16(af[s], bf[s], a, 0, 0, 0);
        acc[t] = a;
    }
}

__global__ __launch_bounds__(512, 4) void mlp_kernel(
    const float* __restrict__ x,
    const short8* __restrict__ pw_in, const float* __restrict__ b_in,
    const short8* __restrict__ pwb0,  const float* __restrict__ bb0,
    const short8* __restrict__ pwb1,  const float* __restrict__ bb1,
    const short8* __restrict__ pwb2,  const float* __restrict__ b_out,
    float* __restrict__ w2buf, float* __restrict__ cbuf)
{
    __shared__ short act[2][16 * 256];   // 2 x 8 KB bf16, swizzled
    char* bufA = (char*)&act[0][0];
    char* bufB = (char*)&act[1][0];
    const int lane = threadIdx.x & 63;
    const int w    = threadIdx.x >> 6;      // 0..7
    const int li   = lane & 15, g = lane >> 4;
    const int b0i  = blockIdx.x * 8;        // 8 real samples

    f32x4 acc[2];

    // ---- input layer: params(16, zero-padded) -> 256 -> bufA ----
    {
        short8 a0 = {0, 0, 0, 0, 0, 0, 0, 0};
        if (g < 2 && li < 8) {              // rows 8..15: zero (don't-care)
            const float* xr = x + (b0i + li) * XCOLS + D + g * 8;
            #pragma unroll
            for (int e = 0; e < 8; ++e) a0[e] = (short)rne16(xr[e]);
        }
        #pragma unroll
        for (int t = 0; t < 2; ++t) {
            float bb = b_in[(2 * w + t) * 16 + li];
            f32x4 tmp = {bb, bb, bb, bb};
            short8 bfr = pw_in[(2 * w + t) * 64 + lane];
            acc[t] = __builtin_amdgcn_mfma_f32_16x16x32_bf16(a0, bfr, tmp, 0, 0, 0);
        }
        store_act16(bufA, acc, li, g, w, true);
    }
    __syncthreads();

    hidden_layer16(bufA, pwb0, bb0, lane, li, g, w, acc);
    store_act16(bufB, acc, li, g, w, true);
    __syncthreads();

    hidden_layer16(bufB, pwb1, bb1, lane, li, g, w, acc);
    store_act16(bufA, acc, li, g, w, true);
    __syncthreads();

    hidden_layer16(bufA, pwb2, b_out, lane, li, g, w, acc);  // coef, no relu

    // ---- epilogue: j = (2w+t)*16+li; sample b = b0i + g*4 + r (g<2 only) ----
    if (g < 2) {
        #pragma unroll
        for (int t = 0; t < 2; ++t) {
            int j = (2 * w + t) * 16 + li;
            #pragma unroll
            for (int r = 0; r < 4; ++r) {
                int b = b0i + g * 4 + r;
                float c = acc[t][r];
                if (j < D) {
                    float om = fmaf(c, 1.5f, 0.5f);
                    w2buf[b * D + j] = om * om * INV_2PI_F;
                } else {
                    cbuf[b * D + (j - D)] = c;
                }
            }
        }
    }
}

// ---------------- ODE: revolution-domain RK4, 2 samples per wave -------------

__device__ __forceinline__ float rot_from_lower(float v) {  // lane n <- lane (n-1)&63
    return __int_as_float(__builtin_amdgcn_mov_dpp(__float_as_int(v), 0x13C, 0xF, 0xF, false)); // wave_ror:1
}
__device__ __forceinline__ float rot_from_upper(float v) {  // lane n <- lane (n+1)&63
    return __int_as_float(__builtin_amdgcn_mov_dpp(__float_as_int(v), 0x134, 0xF, 0xF, false)); // wave_rol:1
}

__global__ __launch_bounds__(256) void ode_kernel(
    const float* __restrict__ x,
    const float* __restrict__ w2buf,
    const float* __restrict__ cbuf,
    float* __restrict__ out,
    int nstep, float dt)
{
    const int lane = threadIdx.x & 63;
    const int wid  = threadIdx.x >> 6;
    const int bA   = blockIdx.x * 8 + wid * 2;   // two consecutive samples

    float th0[2], th1[2], v0[2], v1[2];
    float nw0[2], nw1[2], c0[2], c1[2], cl[2];

    #pragma unroll
    for (int s = 0; s < 2; ++s) {
        int b  = bA + s;
        int i0 = b * D + 2 * lane;
        float2 xi  = *reinterpret_cast<const float2*>(&x[b * XCOLS + 2 * lane]);
        th0[s] = xi.x - 0.5f;            // phi0 = x - 1/2 (revolutions)
        th1[s] = xi.y - 0.5f;
        v0[s] = 0.f; v1[s] = 0.f;
        float2 w2p = *reinterpret_cast<const float2*>(&w2buf[i0]);
        float2 cp  = *reinterpret_cast<const float2*>(&cbuf[i0]);
        nw0[s] = -w2p.x; nw1[s] = -w2p.y;
        c0[s] = cp.x;    c1[s] = cp.y;
        cl[s] = cbuf[(i0 + NTOT - 1) & (NTOT - 1)];   // flat-roll left coupling
    }

    auto deriv = [&](const float t0[2], const float t1[2], float a0[2], float a1[2]) {
        #pragma unroll
        for (int s = 0; s < 2; ++s) {
            float L0 = rot_from_lower(t1[s]);   // phi of osc 2l-1 (wraps 0 -> 127)
            float R1 = rot_from_upper(t0[s]);   // phi of osc 2l+2 (wraps 63 -> 0)
            float s0 = __builtin_amdgcn_sinf(t0[s]);   // sin(2pi*phi), raw v_sin_f32
            float s1 = __builtin_amdgcn_sinf(t1[s]);
            float dd  = t1[s] - t0[s];
            float cpl = c0[s] * dd;
            a0[s] = fmaf(s0, nw0[s], fmaf(cl[s], L0 - t0[s],  cpl));
            a1[s] = fmaf(s1, nw1[s], fmaf(c1[s], R1 - t1[s], -cpl));
        }
    };

    const float hdt   = 0.5f * dt;
    const float sixth = dt * (1.0f / 6.0f);

    for (int it = 0; it < nstep; ++it) {
        float a1_0[2], a1_1[2];
        deriv(th0, th1, a1_0, a1_1);

        float t2_0[2], t2_1[2], k2_0[2], k2_1[2];
        #pragma unroll
        for (int s = 0; s < 2; ++s) {
            t2_0[s] = fmaf(hdt, v0[s], th0[s]);   t2_1[s] = fmaf(hdt, v1[s], th1[s]);
            k2_0[s] = fmaf(hdt, a1_0[s], v0[s]);  k2_1[s] = fmaf(hdt, a1_1[s], v1[s]);
        }
        float a2_0[2], a2_1[2];
        deriv(t2_0, t2_1, a2_0, a2_1);

        float t3_0[2], t3_1[2], k3_0[2], k3_1[2];
        #pragma unroll
        for (int s = 0; s < 2; ++s) {
            t3_0[s] = fmaf(hdt, k2_0[s], th0[s]); t3_1[s] = fmaf(hdt, k2_1[s], th1[s]);
            k3_0[s] = fmaf(hdt, a2_0[s], v0[s]);  k3_1[s] = fmaf(hdt, a2_1[s], v1[s]);
        }
        float a3_0[2], a3_1[2];
        deriv(t3_0, t3_1, a3_0, a3_1);

        float t4_0[2], t4_1[2], k4_0[2], k4_1[2];
        #pragma unroll
        for (int s = 0; s < 2; ++s) {
            t4_0[s] = fmaf(dt, k3_0[s], th0[s]);  t4_1[s] = fmaf(dt, k3_1[s], th1[s]);
            k4_0[s] = fmaf(dt, a3_0[s], v0[s]);   k4_1[s] = fmaf(dt, a3_1[s], v1[s]);
        }
        float a4_0[2], a4_1[2];
        deriv(t4_0, t4_1, a4_0, a4_1);

        #pragma unroll
        for (int s = 0; s < 2; ++s) {
            th0[s] += sixth * (v0[s] + 2.f * (k2_0[s] + k3_0[s]) + k4_0[s]);
            th1[s] += sixth * (v1[s] + 2.f * (k2_1[s] + k3_1[s]) + k4_1[s]);
            v0[s]  += sixth * (a1_0[s] + 2.f * (a2_0[s] + a3_0[s]) + a4_0[s]);
            v1[s]  += sixth * (a1_1[s] + 2.f * (a2_1[s] + a3_1[s]) + a4_1[s]);
        }
    }

    #pragma unroll
    for (int s = 0; s < 2; ++s) {
        int i0 = (bA + s) * D + 2 * lane;
        float2 o = make_float2(th0[s] * OUT_SCALE, th1[s] * OUT_SCALE);
        *reinterpret_cast<float2*>(&out[i0]) = o;
    }
}

extern "C" void kernel_launch(void* const* d_in, const int* in_sizes, int n_in,
                              void* d_out, int out_size, void* d_ws, size_t ws_size,
                              hipStream_t stream) {
    const float* x     = (const float*)d_in[0];
    const float* w_in  = (const float*)d_in[1];
    const float* b_in  = (const float*)d_in[2];
    const float* w0    = (const float*)d_in[3];
    const float* b0    = (const float*)d_in[4];
    const float* w1    = (const float*)d_in[5];
    const float* b1    = (const float*)d_in[6];
    const float* w_out = (const float*)d_in[7];
    const float* b_out = (const float*)d_in[8];

    float* w2buf = (float*)d_ws;                  // omega0^2/(2pi), NTOT floats
    float* cbuf  = w2buf + NTOT;                  // coupling, NTOT floats
    short8* pw_in = (short8*)(cbuf + NTOT);       // 1024 slots x 16 B
    short8* pwb0  = pw_in + 1024;                 // 8192 slots
    short8* pwb1  = pwb0 + 8192;
    short8* pwb2  = pwb1 + 8192;
    float* out   = (float*)d_out;

    pack_kernel<<<100, 256, 0, stream>>>(w_in, w0, w1, w_out,
                                         pw_in, pwb0, pwb1, pwb2);

    mlp_kernel<<<BATCH / 8, 512, 0, stream>>>(
        x, pw_in, b_in, pwb0, b0, pwb1, b1, pwb2, b_out, w2buf, cbuf);

    const int nstep = 6;
    const float dtf = (float)((59.0 / 30.0) / nstep);
    ode_kernel<<<BATCH / 8, 256, 0, stream>>>(x, w2buf, cbuf, out, nstep, dtf);
}

// Round 15
// 22.296 us; speedup vs baseline: 1.1800x; 1.1800x over previous
//
#include <hip/hip_runtime.h>
#include <math.h>

#define D 128
#define NPARAMS 16
#define H 256
#define XCOLS (D + NPARAMS)   // 144
#define BATCH 4096
#define NTOT (BATCH * D)      // 524288

#define INV_2PI_F 0.15915494309189535f
#define OUT_SCALE 2.5132741228718345f   // 2*pi / 2.5

typedef __attribute__((ext_vector_type(8))) short short8;   // 8 bf16 (4 VGPR)
typedef __attribute__((ext_vector_type(4))) float f32x4;    // MFMA acc

__device__ __forceinline__ unsigned rne16(float x) {        // fp32 -> bf16 RNE
    unsigned u = __float_as_uint(x);
    return (u + 0x7fffu + ((u >> 16) & 1u)) >> 16;
}

// ---------------- weight pre-pack into MFMA B-fragments (bf16) ---------------
// B-frag slot (ntile t, kstep s, lane l): B[k][j] = W[j][k],
// j = 16t + (l&15), k = 32s + (l>>4)*8 + e.

__global__ __launch_bounds__(256) void pack_kernel(
    const float* __restrict__ w_in, const float* __restrict__ w0,
    const float* __restrict__ w1,   const float* __restrict__ w_out,
    short8* __restrict__ pw_in, short8* __restrict__ pwb0,
    short8* __restrict__ pwb1,  short8* __restrict__ pwb2)
{
    int tid = blockIdx.x * 256 + threadIdx.x;
    if (tid < 24576) {                      // 3 matrices x 8192 slots
        const float* W = (tid < 8192) ? w0 : (tid < 16384) ? w1 : w_out;
        short8* P      = (tid < 8192) ? pwb0 : (tid < 16384) ? pwb1 : pwb2;
        int slot = tid & 8191;
        int l = slot & 63, ts = slot >> 6;
        int s = ts & 7, t = ts >> 3;
        int j = 16 * t + (l & 15);
        int kb = 32 * s + ((l >> 4) << 3);
        const float* src = W + j * H + kb;
        short8 v;
        #pragma unroll
        for (int e = 0; e < 8; ++e) v[e] = (short)rne16(src[e]);
        P[slot] = v;
    } else if (tid < 25600) {               // input layer: 1024 slots, K=16 pad
        int slot = tid - 24576;
        int l = slot & 63, t = slot >> 6;
        int j = 16 * t + (l & 15), gg = l >> 4;
        short8 v = {0, 0, 0, 0, 0, 0, 0, 0};
        if (gg < 2) {
            const float* src = w_in + j * NPARAMS + gg * 8;
            #pragma unroll
            for (int e = 0; e < 8; ++e) v[e] = (short)rne16(src[e]);
        }
        pw_in[slot] = v;
    }
}

// ---------------- MFMA MLP, software-pipelined B-fragments (R13 core) --------
// Block = 512 thr (8 waves) x 16 samples; wave w owns n-tiles 2w, 2w+1.
// Acts in LDS as bf16 [16][256] (512 B rows, XOR swizzle byte ^= (row&7)<<4).
// Layer n+1's B-frag loads are issued BEFORE layer n's barrier so their
// L2 latency drains under store/barrier/A-reads/MFMA of the previous layer.
// x-params staged once per block via coalesced LDS (no redundant wave loads).

__device__ __forceinline__ int act_addr(int row, int colbyte) {
    return (row * 512 + colbyte) ^ ((row & 7) << 4);
}

__device__ __forceinline__ short8 load_afrag16(const char* actb, int li, int g, int s) {
    return *reinterpret_cast<const short8*>(actb + act_addr(li, s * 64 + g * 16));
}

__device__ __forceinline__ void store_act16(char* actb, const f32x4 acc[2],
                                            int li, int g, int w, bool relu) {
    #pragma unroll
    for (int t = 0; t < 2; ++t) {
        int col = (2 * w + t) * 16 + li;
        #pragma unroll
        for (int r = 0; r < 4; ++r) {
            int row = g * 4 + r;
            float v = relu ? fmaxf(acc[t][r], 0.f) : acc[t][r];
            *reinterpret_cast<short*>(actb + act_addr(row, col * 2)) = (short)rne16(v);
        }
    }
}

__device__ __forceinline__ void hidden_compute(
    const char* actb, const short8 (&bf)[2][8], const float bias[2],
    int li, int g, f32x4 acc[2])
{
    short8 af[8];
    #pragma unroll
    for (int s = 0; s < 8; ++s) af[s] = load_afrag16(actb, li, g, s);
    #pragma unroll
    for (int t = 0; t < 2; ++t) {
        f32x4 tmp = {bias[t], bias[t], bias[t], bias[t]};
        acc[t] = tmp;
    }
    #pragma unroll
    for (int s = 0; s < 8; ++s)
        #pragma unroll
        for (int t = 0; t < 2; ++t)
            acc[t] = __builtin_amdgcn_mfma_f32_16x16x32_bf16(af[s], bf[t][s], acc[t], 0, 0, 0);
}

__global__ __launch_bounds__(512, 1) void mlp_kernel(
    const float* __restrict__ x,
    const short8* __restrict__ pw_in, const float* __restrict__ b_in,
    const short8* __restrict__ pwb0,  const float* __restrict__ bb0,
    const short8* __restrict__ pwb1,  const float* __restrict__ bb1,
    const short8* __restrict__ pwb2,  const float* __restrict__ b_out,
    float* __restrict__ w2buf, float* __restrict__ cbuf)
{
    __shared__ short act[2][16 * 256];   // 2 x 8 KB bf16, swizzled
    __shared__ float xs[16][16];         // staged params
    char* bufA = (char*)&act[0][0];
    char* bufB = (char*)&act[1][0];
    const int lane = threadIdx.x & 63;
    const int w    = threadIdx.x >> 6;      // 0..7
    const int li   = lane & 15, g = lane >> 4;
    const int b0i  = blockIdx.x * 16;

    // ---- stage x params coalesced: 256 threads cover 16x16 ----
    if (threadIdx.x < 256) {
        int r = threadIdx.x >> 4, c = threadIdx.x & 15;
        xs[r][c] = x[(b0i + r) * XCOLS + D + c];
    }

    // ---- issue ALL early loads up front ----
    short8 bin[2];
    #pragma unroll
    for (int t = 0; t < 2; ++t) bin[t] = pw_in[(2 * w + t) * 64 + lane];

    short8 bA[2][8], bB[2][8];
    #pragma unroll
    for (int t = 0; t < 2; ++t)
        #pragma unroll
        for (int s = 0; s < 8; ++s)
            bA[t][s] = pwb0[((2 * w + t) * 8 + s) * 64 + lane];   // layer0 frags

    float bias_in[2], bias0[2], bias1[2], bias2[2];
    #pragma unroll
    for (int t = 0; t < 2; ++t) {
        int j16 = (2 * w + t) * 16 + li;
        bias_in[t] = b_in[j16];
        bias0[t]   = bb0[j16];
        bias1[t]   = bb1[j16];
        bias2[t]   = b_out[j16];
    }
    __syncthreads();   // xs ready

    short8 a0 = {0, 0, 0, 0, 0, 0, 0, 0};
    if (g < 2) {
        #pragma unroll
        for (int e = 0; e < 8; ++e) a0[e] = (short)rne16(xs[li][g * 8 + e]);
    }

    f32x4 acc[2];

    // ---- input layer: params -> 256 -> bufA ----
    #pragma unroll
    for (int t = 0; t < 2; ++t) {
        f32x4 tmp = {bias_in[t], bias_in[t], bias_in[t], bias_in[t]};
        acc[t] = __builtin_amdgcn_mfma_f32_16x16x32_bf16(a0, bin[t], tmp, 0, 0, 0);
    }
    store_act16(bufA, acc, li, g, w, true);

    // prefetch layer1 frags before the barrier
    #pragma unroll
    for (int t = 0; t < 2; ++t)
        #pragma unroll
        for (int s = 0; s < 8; ++s)
            bB[t][s] = pwb1[((2 * w + t) * 8 + s) * 64 + lane];
    __syncthreads();

    // ---- layer 0: read bufA, MFMA with bA ----
    hidden_compute(bufA, bA, bias0, li, g, acc);
    store_act16(bufB, acc, li, g, w, true);
    // prefetch layer2 frags (bA registers free after the MFMAs above)
    #pragma unroll
    for (int t = 0; t < 2; ++t)
        #pragma unroll
        for (int s = 0; s < 8; ++s)
            bA[t][s] = pwb2[((2 * w + t) * 8 + s) * 64 + lane];
    __syncthreads();

    // ---- layer 1: read bufB, MFMA with bB ----
    hidden_compute(bufB, bB, bias1, li, g, acc);
    store_act16(bufA, acc, li, g, w, true);
    __syncthreads();

    // ---- layer 2 (out): read bufA, MFMA with bA -> coef ----
    hidden_compute(bufA, bA, bias2, li, g, acc);

    // ---- epilogue: j = (2w+t)*16+li; sample b = b0i + g*4 + r ----
    #pragma unroll
    for (int t = 0; t < 2; ++t) {
        int j = (2 * w + t) * 16 + li;
        #pragma unroll
        for (int r = 0; r < 4; ++r) {
            int b = b0i + g * 4 + r;
            float c = acc[t][r];
            if (j < D) {
                float om = fmaf(c, 1.5f, 0.5f);
                w2buf[b * D + j] = om * om * INV_2PI_F;
            } else {
                cbuf[b * D + (j - D)] = c;
            }
        }
    }
}

// ---------------- ODE: revolution-domain RK4, 2 samples per wave -------------

__device__ __forceinline__ float rot_from_lower(float v) {  // lane n <- lane (n-1)&63
    return __int_as_float(__builtin_amdgcn_mov_dpp(__float_as_int(v), 0x13C, 0xF, 0xF, false)); // wave_ror:1
}
__device__ __forceinline__ float rot_from_upper(float v) {  // lane n <- lane (n+1)&63
    return __int_as_float(__builtin_amdgcn_mov_dpp(__float_as_int(v), 0x134, 0xF, 0xF, false)); // wave_rol:1
}

__global__ __launch_bounds__(256) void ode_kernel(
    const float* __restrict__ x,
    const float* __restrict__ w2buf,
    const float* __restrict__ cbuf,
    float* __restrict__ out,
    int nstep, float dt)
{
    const int lane = threadIdx.x & 63;
    const int wid  = threadIdx.x >> 6;
    const int bA   = blockIdx.x * 8 + wid * 2;   // two consecutive samples

    float th0[2], th1[2], v0[2], v1[2];
    float nw0[2], nw1[2], c0[2], c1[2], cl[2];

    #pragma unroll
    for (int s = 0; s < 2; ++s) {
        int b  = bA + s;
        int i0 = b * D + 2 * lane;
        float2 xi  = *reinterpret_cast<const float2*>(&x[b * XCOLS + 2 * lane]);
        th0[s] = xi.x - 0.5f;            // phi0 = x - 1/2 (revolutions)
        th1[s] = xi.y - 0.5f;
        v0[s] = 0.f; v1[s] = 0.f;
        float2 w2p = *reinterpret_cast<const float2*>(&w2buf[i0]);
        float2 cp  = *reinterpret_cast<const float2*>(&cbuf[i0]);
        nw0[s] = -w2p.x; nw1[s] = -w2p.y;
        c0[s] = cp.x;    c1[s] = cp.y;
        cl[s] = cbuf[(i0 + NTOT - 1) & (NTOT - 1)];   // flat-roll left coupling
    }

    auto deriv = [&](const float t0[2], const float t1[2], float a0[2], float a1[2]) {
        #pragma unroll
        for (int s = 0; s < 2; ++s) {
            float L0 = rot_from_lower(t1[s]);   // phi of osc 2l-1 (wraps 0 -> 127)
            float R1 = rot_from_upper(t0[s]);   // phi of osc 2l+2 (wraps 63 -> 0)
            float s0 = __builtin_amdgcn_sinf(t0[s]);   // sin(2pi*phi), raw v_sin_f32
            float s1 = __builtin_amdgcn_sinf(t1[s]);
            float dd  = t1[s] - t0[s];
            float cpl = c0[s] * dd;
            a0[s] = fmaf(s0, nw0[s], fmaf(cl[s], L0 - t0[s],  cpl));
            a1[s] = fmaf(s1, nw1[s], fmaf(c1[s], R1 - t1[s], -cpl));
        }
    };

    const float hdt   = 0.5f * dt;
    const float sixth = dt * (1.0f / 6.0f);

    for (int it = 0; it < nstep; ++it) {
        float a1_0[2], a1_1[2];
        deriv(th0, th1, a1_0, a1_1);

        float t2_0[2], t2_1[2], k2_0[2], k2_1[2];
        #pragma unroll
        for (int s = 0; s < 2; ++s) {
            t2_0[s] = fmaf(hdt, v0[s], th0[s]);   t2_1[s] = fmaf(hdt, v1[s], th1[s]);
            k2_0[s] = fmaf(hdt, a1_0[s], v0[s]);  k2_1[s] = fmaf(hdt, a1_1[s], v1[s]);
        }
        float a2_0[2], a2_1[2];
        deriv(t2_0, t2_1, a2_0, a2_1);

        float t3_0[2], t3_1[2], k3_0[2], k3_1[2];
        #pragma unroll
        for (int s = 0; s < 2; ++s) {
            t3_0[s] = fmaf(hdt, k2_0[s], th0[s]); t3_1[s] = fmaf(hdt, k2_1[s], th1[s]);
            k3_0[s] = fmaf(hdt, a2_0[s], v0[s]);  k3_1[s] = fmaf(hdt, a2_1[s], v1[s]);
        }
        float a3_0[2], a3_1[2];
        deriv(t3_0, t3_1, a3_0, a3_1);

        float t4_0[2], t4_1[2], k4_0[2], k4_1[2];
        #pragma unroll
        for (int s = 0; s < 2; ++s) {
            t4_0[s] = fmaf(dt, k3_0[s], th0[s]);  t4_1[s] = fmaf(dt, k3_1[s], th1[s]);
            k4_0[s] = fmaf(dt, a3_0[s], v0[s]);   k4_1[s] = fmaf(dt, a3_1[s], v1[s]);
        }
        float a4_0[2], a4_1[2];
        deriv(t4_0, t4_1, a4_0, a4_1);

        #pragma unroll
        for (int s = 0; s < 2; ++s) {
            th0[s] += sixth * (v0[s] + 2.f * (k2_0[s] + k3_0[s]) + k4_0[s]);
            th1[s] += sixth * (v1[s] + 2.f * (k2_1[s] + k3_1[s]) + k4_1[s]);
            v0[s]  += sixth * (a1_0[s] + 2.f * (a2_0[s] + a3_0[s]) + a4_0[s]);
            v1[s]  += sixth * (a1_1[s] + 2.f * (a2_1[s] + a3_1[s]) + a4_1[s]);
        }
    }

    #pragma unroll
    for (int s = 0; s < 2; ++s) {
        int i0 = (bA + s) * D + 2 * lane;
        float2 o = make_float2(th0[s] * OUT_SCALE, th1[s] * OUT_SCALE);
        *reinterpret_cast<float2*>(&out[i0]) = o;
    }
}

extern "C" void kernel_launch(void* const* d_in, const int* in_sizes, int n_in,
                              void* d_out, int out_size, void* d_ws, size_t ws_size,
                              hipStream_t stream) {
    const float* x     = (const float*)d_in[0];
    const float* w_in  = (const float*)d_in[1];
    const float* b_in  = (const float*)d_in[2];
    const float* w0    = (const float*)d_in[3];
    const float* b0    = (const float*)d_in[4];
    const float* w1    = (const float*)d_in[5];
    const float* b1    = (const float*)d_in[6];
    const float* w_out = (const float*)d_in[7];
    const float* b_out = (const float*)d_in[8];

    float* w2buf = (float*)d_ws;                  // omega0^2/(2pi), NTOT floats
    float* cbuf  = w2buf + NTOT;                  // coupling, NTOT floats
    short8* pw_in = (short8*)(cbuf + NTOT);       // 1024 slots x 16 B
    short8* pwb0  = pw_in + 1024;                 // 8192 slots
    short8* pwb1  = pwb0 + 8192;
    short8* pwb2  = pwb1 + 8192;
    float* out   = (float*)d_out;

    pack_kernel<<<100, 256, 0, stream>>>(w_in, w0, w1, w_out,
                                         pw_in, pwb0, pwb1, pwb2);

    mlp_kernel<<<BATCH / 16, 512, 0, stream>>>(
        x, pw_in, b_in, pwb0, b0, pwb1, b1, pwb2, b_out, w2buf, cbuf);

    const int nstep = 5;
    const float dtf = (float)((59.0 / 30.0) / nstep);
    ode_kernel<<<BATCH / 8, 256, 0, stream>>>(x, w2buf, cbuf, out, nstep, dtf);
}

// Round 16
// 19.451 us; speedup vs baseline: 1.3526x; 1.1462x over previous
//
#include <hip/hip_runtime.h>
#include <math.h>

#define D 128
#define NPARAMS 16
#define H 256
#define XCOLS (D + NPARAMS)   // 144
#define BATCH 4096
#define NTOT (BATCH * D)      // 524288

#define INV_2PI_F 0.15915494309189535f
#define OUT_SCALE 2.5132741228718345f   // 2*pi / 2.5

typedef __attribute__((ext_vector_type(8))) short short8;   // 8 bf16 (4 VGPR)
typedef __attribute__((ext_vector_type(4))) float f32x4;    // MFMA acc

__device__ __forceinline__ unsigned rne16(float x) {        // fp32 -> bf16 RNE
    unsigned u = __float_as_uint(x);
    return (u + 0x7fffu + ((u >> 16) & 1u)) >> 16;
}

// ---------------- weight pre-pack into MFMA B-fragments (bf16) ---------------
// B-frag slot (ntile t, kstep s, lane l): B[k][j] = W[j][k],
// j = 16t + (l&15), k = 32s + (l>>4)*8 + e.

__global__ __launch_bounds__(256) void pack_kernel(
    const float* __restrict__ w_in, const float* __restrict__ w0,
    const float* __restrict__ w1,   const float* __restrict__ w_out,
    short8* __restrict__ pw_in, short8* __restrict__ pwb0,
    short8* __restrict__ pwb1,  short8* __restrict__ pwb2)
{
    int tid = blockIdx.x * 256 + threadIdx.x;
    if (tid < 24576) {                      // 3 matrices x 8192 slots
        const float* W = (tid < 8192) ? w0 : (tid < 16384) ? w1 : w_out;
        short8* P      = (tid < 8192) ? pwb0 : (tid < 16384) ? pwb1 : pwb2;
        int slot = tid & 8191;
        int l = slot & 63, ts = slot >> 6;
        int s = ts & 7, t = ts >> 3;
        int j = 16 * t + (l & 15);
        int kb = 32 * s + ((l >> 4) << 3);
        const float* src = W + j * H + kb;
        short8 v;
        #pragma unroll
        for (int e = 0; e < 8; ++e) v[e] = (short)rne16(src[e]);
        P[slot] = v;
    } else if (tid < 25600) {               // input layer: 1024 slots, K=16 pad
        int slot = tid - 24576;
        int l = slot & 63, t = slot >> 6;
        int j = 16 * t + (l & 15), gg = l >> 4;
        short8 v = {0, 0, 0, 0, 0, 0, 0, 0};
        if (gg < 2) {
            const float* src = w_in + j * NPARAMS + gg * 8;
            #pragma unroll
            for (int e = 0; e < 8; ++e) v[e] = (short)rne16(src[e]);
        }
        pw_in[slot] = v;
    }
}

// ---------------- fused MLP (MFMA) + ODE (RK4) -------------------------------
// 256 blocks x 512 thr. Phase 1: R15's pipelined MFMA MLP for 16 samples PLUS
// a 2nd row-group whose row 0 is the boundary sample b0i-1 (rows 1..15 are
// don't-care garbage; matmul rows are independent). B-frags reused from
// registers -> no extra weight traffic. w2/coupling stay in LDS; the boundary
// coupling coef[255] comes from wave 7's accumulator. Phase 2: RK4 ODE for
// the same 16 samples (8 waves x 2), all inputs from LDS. No cross-block
// communication; boundary math is bit-identical to the split version.

__device__ __forceinline__ int act_addr(int row, int colbyte) {
    return (row * 512 + colbyte) ^ ((row & 7) << 4);
}

__device__ __forceinline__ short8 load_afrag16(const char* actb, int li, int g, int s) {
    return *reinterpret_cast<const short8*>(actb + act_addr(li, s * 64 + g * 16));
}

__device__ __forceinline__ void store_act16(char* actb, const f32x4 acc[2],
                                            int li, int g, int w, bool relu) {
    #pragma unroll
    for (int t = 0; t < 2; ++t) {
        int col = (2 * w + t) * 16 + li;
        #pragma unroll
        for (int r = 0; r < 4; ++r) {
            int row = g * 4 + r;
            float v = relu ? fmaxf(acc[t][r], 0.f) : acc[t][r];
            *reinterpret_cast<short*>(actb + act_addr(row, col * 2)) = (short)rne16(v);
        }
    }
}

__device__ __forceinline__ void compute_tile(
    const char* actb, const short8 (&bf)[2][8], const float bias[2],
    int li, int g, f32x4 acc[2])
{
    short8 af[8];
    #pragma unroll
    for (int s = 0; s < 8; ++s) af[s] = load_afrag16(actb, li, g, s);
    #pragma unroll
    for (int t = 0; t < 2; ++t) {
        f32x4 tmp = {bias[t], bias[t], bias[t], bias[t]};
        acc[t] = tmp;
    }
    #pragma unroll
    for (int s = 0; s < 8; ++s)
        #pragma unroll
        for (int t = 0; t < 2; ++t)
            acc[t] = __builtin_amdgcn_mfma_f32_16x16x32_bf16(af[s], bf[t][s], acc[t], 0, 0, 0);
}

__device__ __forceinline__ float rot_from_lower(float v) {  // lane n <- lane (n-1)&63
    return __int_as_float(__builtin_amdgcn_mov_dpp(__float_as_int(v), 0x13C, 0xF, 0xF, false)); // wave_ror:1
}
__device__ __forceinline__ float rot_from_upper(float v) {  // lane n <- lane (n+1)&63
    return __int_as_float(__builtin_amdgcn_mov_dpp(__float_as_int(v), 0x134, 0xF, 0xF, false)); // wave_rol:1
}

__global__ __launch_bounds__(512, 1) void fused_kernel(
    const float* __restrict__ x,
    const short8* __restrict__ pw_in, const float* __restrict__ b_in,
    const short8* __restrict__ pwb0,  const float* __restrict__ bb0,
    const short8* __restrict__ pwb1,  const float* __restrict__ bb1,
    const short8* __restrict__ pwb2,  const float* __restrict__ b_out,
    float* __restrict__ out, int nstep, float dt)
{
    __shared__ short act1[2][16 * 256];   // rg1 ping/pong (8 KB each)
    __shared__ short act2[2][16 * 256];   // rg2 (boundary) ping/pong
    __shared__ float xs[17][16];          // params; row 16 = boundary sample
    __shared__ float w2_lds[16][128];     // omega0^2/(2pi) per local sample
    __shared__ float c_lds[16][128];      // coupling per local sample
    __shared__ float c_bnd;               // coupling[127] of boundary sample

    char* b1A = (char*)&act1[0][0];
    char* b1B = (char*)&act1[1][0];
    char* b2A = (char*)&act2[0][0];
    char* b2B = (char*)&act2[1][0];
    const int lane = threadIdx.x & 63;
    const int w    = threadIdx.x >> 6;      // 0..7
    const int li   = lane & 15, g = lane >> 4;
    const int b0i  = blockIdx.x * 16;

    // ---- stage params coalesced (17 rows x 16 cols) ----
    if (threadIdx.x < 272) {
        int r = threadIdx.x >> 4, c = threadIdx.x & 15;
        int b = (r < 16) ? (b0i + r) : ((b0i + BATCH - 1) & (BATCH - 1));
        xs[r][c] = x[b * XCOLS + D + c];
    }

    // ---- early loads: input-layer frags, layer0 frags, all biases ----
    short8 bin[2];
    #pragma unroll
    for (int t = 0; t < 2; ++t) bin[t] = pw_in[(2 * w + t) * 64 + lane];

    short8 bA[2][8], bB[2][8];
    #pragma unroll
    for (int t = 0; t < 2; ++t)
        #pragma unroll
        for (int s = 0; s < 8; ++s)
            bA[t][s] = pwb0[((2 * w + t) * 8 + s) * 64 + lane];

    float bias_in[2], bias0[2], bias1[2], bias2[2];
    #pragma unroll
    for (int t = 0; t < 2; ++t) {
        int j16 = (2 * w + t) * 16 + li;
        bias_in[t] = b_in[j16];
        bias0[t]   = bb0[j16];
        bias1[t]   = bb1[j16];
        bias2[t]   = b_out[j16];
    }
    __syncthreads();   // xs ready

    // ---- input layer: rg1 (16 samples) + rg2 (boundary in row 0) ----
    short8 a0  = {0, 0, 0, 0, 0, 0, 0, 0};
    short8 a0b = {0, 0, 0, 0, 0, 0, 0, 0};
    if (g < 2) {
        #pragma unroll
        for (int e = 0; e < 8; ++e) a0[e] = (short)rne16(xs[li][g * 8 + e]);
        if (li == 0) {
            #pragma unroll
            for (int e = 0; e < 8; ++e) a0b[e] = (short)rne16(xs[16][g * 8 + e]);
        }
    }

    f32x4 acc[2], acc2[2];
    #pragma unroll
    for (int t = 0; t < 2; ++t) {
        f32x4 tmp = {bias_in[t], bias_in[t], bias_in[t], bias_in[t]};
        acc[t]  = __builtin_amdgcn_mfma_f32_16x16x32_bf16(a0,  bin[t], tmp, 0, 0, 0);
        acc2[t] = __builtin_amdgcn_mfma_f32_16x16x32_bf16(a0b, bin[t], tmp, 0, 0, 0);
    }
    store_act16(b1A, acc,  li, g, w, true);
    store_act16(b2A, acc2, li, g, w, true);

    // prefetch layer1 frags before the barrier
    #pragma unroll
    for (int t = 0; t < 2; ++t)
        #pragma unroll
        for (int s = 0; s < 8; ++s)
            bB[t][s] = pwb1[((2 * w + t) * 8 + s) * 64 + lane];
    __syncthreads();

    // ---- layer 0 (bA) ----
    compute_tile(b1A, bA, bias0, li, g, acc);
    store_act16(b1B, acc, li, g, w, true);
    compute_tile(b2A, bA, bias0, li, g, acc2);
    store_act16(b2B, acc2, li, g, w, true);
    // prefetch layer2 frags
    #pragma unroll
    for (int t = 0; t < 2; ++t)
        #pragma unroll
        for (int s = 0; s < 8; ++s)
            bA[t][s] = pwb2[((2 * w + t) * 8 + s) * 64 + lane];
    __syncthreads();

    // ---- layer 1 (bB) ----
    compute_tile(b1B, bB, bias1, li, g, acc);
    store_act16(b1A, acc, li, g, w, true);
    compute_tile(b2B, bB, bias1, li, g, acc2);
    store_act16(b2A, acc2, li, g, w, true);
    __syncthreads();

    // ---- layer 2 / out (bA = pwb2), no relu ----
    compute_tile(b1A, bA, bias2, li, g, acc);
    compute_tile(b2A, bA, bias2, li, g, acc2);

    // ---- epilogue into LDS ----
    #pragma unroll
    for (int t = 0; t < 2; ++t) {
        int j = (2 * w + t) * 16 + li;
        #pragma unroll
        for (int r = 0; r < 4; ++r) {
            int s = g * 4 + r;               // local sample
            float c = acc[t][r];
            if (j < D) {
                float om = fmaf(c, 1.5f, 0.5f);
                w2_lds[s][j] = om * om * INV_2PI_F;
            } else {
                c_lds[s][j - D] = c;
            }
        }
    }
    if (w == 7 && lane == 15) c_bnd = acc2[1][0];   // ntile15 col15 row0 = coef[255]
    __syncthreads();

    // ================= phase 2: ODE (8 waves x 2 samples) ====================
    float th0[2], th1[2], v0[2], v1[2];
    float nw0[2], nw1[2], c0[2], c1[2], cl[2];

    #pragma unroll
    for (int s = 0; s < 2; ++s) {
        int ls = 2 * w + s;                  // local sample
        int b  = b0i + ls;
        float2 xi = *reinterpret_cast<const float2*>(&x[b * XCOLS + 2 * lane]);
        th0[s] = xi.x - 0.5f;                // phi0 = x - 1/2 (revolutions)
        th1[s] = xi.y - 0.5f;
        v0[s] = 0.f; v1[s] = 0.f;
        nw0[s] = -w2_lds[ls][2 * lane];
        nw1[s] = -w2_lds[ls][2 * lane + 1];
        c0[s]  = c_lds[ls][2 * lane];
        c1[s]  = c_lds[ls][2 * lane + 1];
        cl[s]  = (lane == 0) ? ((ls == 0) ? c_bnd : c_lds[ls - 1][127])
                             : c_lds[ls][2 * lane - 1];
    }

    auto deriv = [&](const float t0[2], const float t1[2], float a0_[2], float a1_[2]) {
        #pragma unroll
        for (int s = 0; s < 2; ++s) {
            float L0 = rot_from_lower(t1[s]);
            float R1 = rot_from_upper(t0[s]);
            float s0 = __builtin_amdgcn_sinf(t0[s]);
            float s1 = __builtin_amdgcn_sinf(t1[s]);
            float dd  = t1[s] - t0[s];
            float cpl = c0[s] * dd;
            a0_[s] = fmaf(s0, nw0[s], fmaf(cl[s], L0 - t0[s],  cpl));
            a1_[s] = fmaf(s1, nw1[s], fmaf(c1[s], R1 - t1[s], -cpl));
        }
    };

    const float hdt   = 0.5f * dt;
    const float sixth = dt * (1.0f / 6.0f);

    for (int it = 0; it < nstep; ++it) {
        float a1_0[2], a1_1[2];
        deriv(th0, th1, a1_0, a1_1);

        float t2_0[2], t2_1[2], k2_0[2], k2_1[2];
        #pragma unroll
        for (int s = 0; s < 2; ++s) {
            t2_0[s] = fmaf(hdt, v0[s], th0[s]);   t2_1[s] = fmaf(hdt, v1[s], th1[s]);
            k2_0[s] = fmaf(hdt, a1_0[s], v0[s]);  k2_1[s] = fmaf(hdt, a1_1[s], v1[s]);
        }
        float a2_0[2], a2_1[2];
        deriv(t2_0, t2_1, a2_0, a2_1);

        float t3_0[2], t3_1[2], k3_0[2], k3_1[2];
        #pragma unroll
        for (int s = 0; s < 2; ++s) {
            t3_0[s] = fmaf(hdt, k2_0[s], th0[s]); t3_1[s] = fmaf(hdt, k2_1[s], th1[s]);
            k3_0[s] = fmaf(hdt, a2_0[s], v0[s]);  k3_1[s] = fmaf(hdt, a2_1[s], v1[s]);
        }
        float a3_0[2], a3_1[2];
        deriv(t3_0, t3_1, a3_0, a3_1);

        float t4_0[2], t4_1[2], k4_0[2], k4_1[2];
        #pragma unroll
        for (int s = 0; s < 2; ++s) {
            t4_0[s] = fmaf(dt, k3_0[s], th0[s]);  t4_1[s] = fmaf(dt, k3_1[s], th1[s]);
            k4_0[s] = fmaf(dt, a3_0[s], v0[s]);   k4_1[s] = fmaf(dt, a3_1[s], v1[s]);
        }
        float a4_0[2], a4_1[2];
        deriv(t4_0, t4_1, a4_0, a4_1);

        #pragma unroll
        for (int s = 0; s < 2; ++s) {
            th0[s] += sixth * (v0[s] + 2.f * (k2_0[s] + k3_0[s]) + k4_0[s]);
            th1[s] += sixth * (v1[s] + 2.f * (k2_1[s] + k3_1[s]) + k4_1[s]);
            v0[s]  += sixth * (a1_0[s] + 2.f * (a2_0[s] + a3_0[s]) + a4_0[s]);
            v1[s]  += sixth * (a1_1[s] + 2.f * (a2_1[s] + a3_1[s]) + a4_1[s]);
        }
    }

    #pragma unroll
    for (int s = 0; s < 2; ++s) {
        int i0 = (b0i + 2 * w + s) * D + 2 * lane;
        float2 o = make_float2(th0[s] * OUT_SCALE, th1[s] * OUT_SCALE);
        *reinterpret_cast<float2*>(&out[i0]) = o;
    }
}

extern "C" void kernel_launch(void* const* d_in, const int* in_sizes, int n_in,
                              void* d_out, int out_size, void* d_ws, size_t ws_size,
                              hipStream_t stream) {
    const float* x     = (const float*)d_in[0];
    const float* w_in  = (const float*)d_in[1];
    const float* b_in  = (const float*)d_in[2];
    const float* w0    = (const float*)d_in[3];
    const float* b0    = (const float*)d_in[4];
    const float* w1    = (const float*)d_in[5];
    const float* b1    = (const float*)d_in[6];
    const float* w_out = (const float*)d_in[7];
    const float* b_out = (const float*)d_in[8];

    short8* pw_in = (short8*)d_ws;                // 1024 slots x 16 B
    short8* pwb0  = pw_in + 1024;                 // 8192 slots
    short8* pwb1  = pwb0 + 8192;
    short8* pwb2  = pwb1 + 8192;
    float* out   = (float*)d_out;

    pack_kernel<<<100, 256, 0, stream>>>(w_in, w0, w1, w_out,
                                         pw_in, pwb0, pwb1, pwb2);

    const int nstep = 5;
    const float dtf = (float)((59.0 / 30.0) / nstep);
    fused_kernel<<<BATCH / 16, 512, 0, stream>>>(
        x, pw_in, b_in, pwb0, b0, pwb1, b1, pwb2, b_out, out, nstep, dtf);
}

// Round 17
// 18.794 us; speedup vs baseline: 1.4000x; 1.0350x over previous
//
#include <hip/hip_runtime.h>
#include <math.h>

#define D 128
#define NPARAMS 16
#define H 256
#define XCOLS (D + NPARAMS)   // 144
#define BATCH 4096
#define NTOT (BATCH * D)      // 524288
#define NSTEP 4

#define INV_2PI_F 0.15915494309189535f
#define OUT_SCALE 2.5132741228718345f   // 2*pi / 2.5

typedef __attribute__((ext_vector_type(8))) short short8;   // 8 bf16 (4 VGPR)
typedef __attribute__((ext_vector_type(4))) float f32x4;    // MFMA acc

__device__ __forceinline__ unsigned rne16(float x) {        // fp32 -> bf16 RNE
    unsigned u = __float_as_uint(x);
    return (u + 0x7fffu + ((u >> 16) & 1u)) >> 16;
}

// ---------------- weight pre-pack into MFMA B-fragments (bf16) ---------------
// B-frag slot (ntile t, kstep s, lane l): B[k][j] = W[j][k],
// j = 16t + (l&15), k = 32s + (l>>4)*8 + e.

__global__ __launch_bounds__(256) void pack_kernel(
    const float* __restrict__ w_in, const float* __restrict__ w0,
    const float* __restrict__ w1,   const float* __restrict__ w_out,
    short8* __restrict__ pw_in, short8* __restrict__ pwb0,
    short8* __restrict__ pwb1,  short8* __restrict__ pwb2)
{
    int tid = blockIdx.x * 256 + threadIdx.x;
    if (tid < 24576) {                      // 3 matrices x 8192 slots
        const float* W = (tid < 8192) ? w0 : (tid < 16384) ? w1 : w_out;
        short8* P      = (tid < 8192) ? pwb0 : (tid < 16384) ? pwb1 : pwb2;
        int slot = tid & 8191;
        int l = slot & 63, ts = slot >> 6;
        int s = ts & 7, t = ts >> 3;
        int j = 16 * t + (l & 15);
        int kb = 32 * s + ((l >> 4) << 3);
        const float* src = W + j * H + kb;
        short8 v;
        #pragma unroll
        for (int e = 0; e < 8; ++e) v[e] = (short)rne16(src[e]);
        P[slot] = v;
    } else if (tid < 25600) {               // input layer: 1024 slots, K=16 pad
        int slot = tid - 24576;
        int l = slot & 63, t = slot >> 6;
        int j = 16 * t + (l & 15), gg = l >> 4;
        short8 v = {0, 0, 0, 0, 0, 0, 0, 0};
        if (gg < 2) {
            const float* src = w_in + j * NPARAMS + gg * 8;
            #pragma unroll
            for (int e = 0; e < 8; ++e) v[e] = (short)rne16(src[e]);
        }
        pw_in[slot] = v;
    }
}

// ---------------- fused MLP (MFMA) + ODE (RK4) -------------------------------
// 256 blocks x 512 thr. Phase 1: pipelined MFMA MLP for 16 samples PLUS a 2nd
// row-group whose row 0 is the boundary sample b0i-1 (rows 1..15 don't-care).
// rg2's final layer runs only on wave 7 (only coef[255] is consumed).
// Phase 2: RK4 ODE for the same 16 samples from LDS. ODE x-inputs prefetched
// into registers at kernel top so the phase boundary has no cold load.

__device__ __forceinline__ int act_addr(int row, int colbyte) {
    return (row * 512 + colbyte) ^ ((row & 7) << 4);
}

__device__ __forceinline__ short8 load_afrag16(const char* actb, int li, int g, int s) {
    return *reinterpret_cast<const short8*>(actb + act_addr(li, s * 64 + g * 16));
}

__device__ __forceinline__ void store_act16(char* actb, const f32x4 acc[2],
                                            int li, int g, int w, bool relu) {
    #pragma unroll
    for (int t = 0; t < 2; ++t) {
        int col = (2 * w + t) * 16 + li;
        #pragma unroll
        for (int r = 0; r < 4; ++r) {
            int row = g * 4 + r;
            float v = relu ? fmaxf(acc[t][r], 0.f) : acc[t][r];
            *reinterpret_cast<short*>(actb + act_addr(row, col * 2)) = (short)rne16(v);
        }
    }
}

__device__ __forceinline__ void compute_tile(
    const char* actb, const short8 (&bf)[2][8], const float bias[2],
    int li, int g, f32x4 acc[2])
{
    short8 af[8];
    #pragma unroll
    for (int s = 0; s < 8; ++s) af[s] = load_afrag16(actb, li, g, s);
    #pragma unroll
    for (int t = 0; t < 2; ++t) {
        f32x4 tmp = {bias[t], bias[t], bias[t], bias[t]};
        acc[t] = tmp;
    }
    #pragma unroll
    for (int s = 0; s < 8; ++s)
        #pragma unroll
        for (int t = 0; t < 2; ++t)
            acc[t] = __builtin_amdgcn_mfma_f32_16x16x32_bf16(af[s], bf[t][s], acc[t], 0, 0, 0);
}

__device__ __forceinline__ float rot_from_lower(float v) {  // lane n <- lane (n-1)&63
    return __int_as_float(__builtin_amdgcn_mov_dpp(__float_as_int(v), 0x13C, 0xF, 0xF, false)); // wave_ror:1
}
__device__ __forceinline__ float rot_from_upper(float v) {  // lane n <- lane (n+1)&63
    return __int_as_float(__builtin_amdgcn_mov_dpp(__float_as_int(v), 0x134, 0xF, 0xF, false)); // wave_rol:1
}

__global__ __launch_bounds__(512, 1) void fused_kernel(
    const float* __restrict__ x,
    const short8* __restrict__ pw_in, const float* __restrict__ b_in,
    const short8* __restrict__ pwb0,  const float* __restrict__ bb0,
    const short8* __restrict__ pwb1,  const float* __restrict__ bb1,
    const short8* __restrict__ pwb2,  const float* __restrict__ b_out,
    float* __restrict__ out, float dt)
{
    __shared__ short act1[2][16 * 256];   // rg1 ping/pong (8 KB each)
    __shared__ short act2[2][16 * 256];   // rg2 (boundary) ping/pong
    __shared__ float xs[17][16];          // params; row 16 = boundary sample
    __shared__ float w2_lds[16][128];     // omega0^2/(2pi) per local sample
    __shared__ float c_lds[16][128];      // coupling per local sample
    __shared__ float c_bnd;               // coupling[127] of boundary sample

    char* b1A = (char*)&act1[0][0];
    char* b1B = (char*)&act1[1][0];
    char* b2A = (char*)&act2[0][0];
    char* b2B = (char*)&act2[1][0];
    const int lane = threadIdx.x & 63;
    const int w    = threadIdx.x >> 6;      // 0..7
    const int li   = lane & 15, g = lane >> 4;
    const int b0i  = blockIdx.x * 16;

    // ---- prefetch ODE initial-condition inputs (consumed in phase 2) ----
    float2 xi_pre[2];
    #pragma unroll
    for (int s = 0; s < 2; ++s)
        xi_pre[s] = *reinterpret_cast<const float2*>(
            &x[(b0i + 2 * w + s) * XCOLS + 2 * lane]);

    // ---- stage params coalesced (17 rows x 16 cols) ----
    if (threadIdx.x < 272) {
        int r = threadIdx.x >> 4, c = threadIdx.x & 15;
        int b = (r < 16) ? (b0i + r) : ((b0i + BATCH - 1) & (BATCH - 1));
        xs[r][c] = x[b * XCOLS + D + c];
    }

    // ---- early loads: input-layer frags, layer0 frags, all biases ----
    short8 bin[2];
    #pragma unroll
    for (int t = 0; t < 2; ++t) bin[t] = pw_in[(2 * w + t) * 64 + lane];

    short8 bA[2][8], bB[2][8];
    #pragma unroll
    for (int t = 0; t < 2; ++t)
        #pragma unroll
        for (int s = 0; s < 8; ++s)
            bA[t][s] = pwb0[((2 * w + t) * 8 + s) * 64 + lane];

    float bias_in[2], bias0[2], bias1[2], bias2[2];
    #pragma unroll
    for (int t = 0; t < 2; ++t) {
        int j16 = (2 * w + t) * 16 + li;
        bias_in[t] = b_in[j16];
        bias0[t]   = bb0[j16];
        bias1[t]   = bb1[j16];
        bias2[t]   = b_out[j16];
    }
    __syncthreads();   // xs ready

    // ---- input layer: rg1 (16 samples) + rg2 (boundary in row 0) ----
    short8 a0  = {0, 0, 0, 0, 0, 0, 0, 0};
    short8 a0b = {0, 0, 0, 0, 0, 0, 0, 0};
    if (g < 2) {
        #pragma unroll
        for (int e = 0; e < 8; ++e) a0[e] = (short)rne16(xs[li][g * 8 + e]);
        if (li == 0) {
            #pragma unroll
            for (int e = 0; e < 8; ++e) a0b[e] = (short)rne16(xs[16][g * 8 + e]);
        }
    }

    f32x4 acc[2], acc2[2];
    #pragma unroll
    for (int t = 0; t < 2; ++t) {
        f32x4 tmp = {bias_in[t], bias_in[t], bias_in[t], bias_in[t]};
        acc[t]  = __builtin_amdgcn_mfma_f32_16x16x32_bf16(a0,  bin[t], tmp, 0, 0, 0);
        acc2[t] = __builtin_amdgcn_mfma_f32_16x16x32_bf16(a0b, bin[t], tmp, 0, 0, 0);
    }
    store_act16(b1A, acc,  li, g, w, true);
    store_act16(b2A, acc2, li, g, w, true);

    // prefetch layer1 frags before the barrier
    #pragma unroll
    for (int t = 0; t < 2; ++t)
        #pragma unroll
        for (int s = 0; s < 8; ++s)
            bB[t][s] = pwb1[((2 * w + t) * 8 + s) * 64 + lane];
    __syncthreads();

    // ---- layer 0 (bA) ----
    compute_tile(b1A, bA, bias0, li, g, acc);
    store_act16(b1B, acc, li, g, w, true);
    compute_tile(b2A, bA, bias0, li, g, acc2);
    store_act16(b2B, acc2, li, g, w, true);
    // prefetch layer2 frags
    #pragma unroll
    for (int t = 0; t < 2; ++t)
        #pragma unroll
        for (int s = 0; s < 8; ++s)
            bA[t][s] = pwb2[((2 * w + t) * 8 + s) * 64 + lane];
    __syncthreads();

    // ---- layer 1 (bB) ----
    compute_tile(b1B, bB, bias1, li, g, acc);
    store_act16(b1A, acc, li, g, w, true);
    compute_tile(b2B, bB, bias1, li, g, acc2);
    store_act16(b2A, acc2, li, g, w, true);
    __syncthreads();

    // ---- layer 2 / out (bA = pwb2), no relu; rg2 only on wave 7 ----
    compute_tile(b1A, bA, bias2, li, g, acc);
    if (w == 7) compute_tile(b2A, bA, bias2, li, g, acc2);

    // ---- epilogue into LDS ----
    #pragma unroll
    for (int t = 0; t < 2; ++t) {
        int j = (2 * w + t) * 16 + li;
        #pragma unroll
        for (int r = 0; r < 4; ++r) {
            int s = g * 4 + r;               // local sample
            float c = acc[t][r];
            if (j < D) {
                float om = fmaf(c, 1.5f, 0.5f);
                w2_lds[s][j] = om * om * INV_2PI_F;
            } else {
                c_lds[s][j - D] = c;
            }
        }
    }
    if (w == 7 && lane == 15) c_bnd = acc2[1][0];   // ntile15 col15 row0 = coef[255]
    __syncthreads();

    // ================= phase 2: ODE (8 waves x 2 samples) ====================
    float th0[2], th1[2], v0[2], v1[2];
    float nw0[2], nw1[2], c0[2], c1[2], cl[2];

    #pragma unroll
    for (int s = 0; s < 2; ++s) {
        int ls = 2 * w + s;                  // local sample
        th0[s] = xi_pre[s].x - 0.5f;         // phi0 = x - 1/2 (revolutions)
        th1[s] = xi_pre[s].y - 0.5f;
        v0[s] = 0.f; v1[s] = 0.f;
        nw0[s] = -w2_lds[ls][2 * lane];
        nw1[s] = -w2_lds[ls][2 * lane + 1];
        c0[s]  = c_lds[ls][2 * lane];
        c1[s]  = c_lds[ls][2 * lane + 1];
        cl[s]  = (lane == 0) ? ((ls == 0) ? c_bnd : c_lds[ls - 1][127])
                             : c_lds[ls][2 * lane - 1];
    }

    auto deriv = [&](const float t0[2], const float t1[2], float a0_[2], float a1_[2]) {
        #pragma unroll
        for (int s = 0; s < 2; ++s) {
            float L0 = rot_from_lower(t1[s]);
            float R1 = rot_from_upper(t0[s]);
            float s0 = __builtin_amdgcn_sinf(t0[s]);
            float s1 = __builtin_amdgcn_sinf(t1[s]);
            float dd  = t1[s] - t0[s];
            float cpl = c0[s] * dd;
            a0_[s] = fmaf(s0, nw0[s], fmaf(cl[s], L0 - t0[s],  cpl));
            a1_[s] = fmaf(s1, nw1[s], fmaf(c1[s], R1 - t1[s], -cpl));
        }
    };

    const float hdt   = 0.5f * dt;
    const float sixth = dt * (1.0f / 6.0f);

    #pragma unroll
    for (int it = 0; it < NSTEP; ++it) {
        float a1_0[2], a1_1[2];
        deriv(th0, th1, a1_0, a1_1);

        float t2_0[2], t2_1[2], k2_0[2], k2_1[2];
        #pragma unroll
        for (int s = 0; s < 2; ++s) {
            t2_0[s] = fmaf(hdt, v0[s], th0[s]);   t2_1[s] = fmaf(hdt, v1[s], th1[s]);
            k2_0[s] = fmaf(hdt, a1_0[s], v0[s]);  k2_1[s] = fmaf(hdt, a1_1[s], v1[s]);
        }
        float a2_0[2], a2_1[2];
        deriv(t2_0, t2_1, a2_0, a2_1);

        float t3_0[2], t3_1[2], k3_0[2], k3_1[2];
        #pragma unroll
        for (int s = 0; s < 2; ++s) {
            t3_0[s] = fmaf(hdt, k2_0[s], th0[s]); t3_1[s] = fmaf(hdt, k2_1[s], th1[s]);
            k3_0[s] = fmaf(hdt, a2_0[s], v0[s]);  k3_1[s] = fmaf(hdt, a2_1[s], v1[s]);
        }
        float a3_0[2], a3_1[2];
        deriv(t3_0, t3_1, a3_0, a3_1);

        float t4_0[2], t4_1[2], k4_0[2], k4_1[2];
        #pragma unroll
        for (int s = 0; s < 2; ++s) {
            t4_0[s] = fmaf(dt, k3_0[s], th0[s]);  t4_1[s] = fmaf(dt, k3_1[s], th1[s]);
            k4_0[s] = fmaf(dt, a3_0[s], v0[s]);   k4_1[s] = fmaf(dt, a3_1[s], v1[s]);
        }
        float a4_0[2], a4_1[2];
        deriv(t4_0, t4_1, a4_0, a4_1);

        #pragma unroll
        for (int s = 0; s < 2; ++s) {
            th0[s] += sixth * (v0[s] + 2.f * (k2_0[s] + k3_0[s]) + k4_0[s]);
            th1[s] += sixth * (v1[s] + 2.f * (k2_1[s] + k3_1[s]) + k4_1[s]);
            v0[s]  += sixth * (a1_0[s] + 2.f * (a2_0[s] + a3_0[s]) + a4_0[s]);
            v1[s]  += sixth * (a1_1[s] + 2.f * (a2_1[s] + a3_1[s]) + a4_1[s]);
        }
    }

    #pragma unroll
    for (int s = 0; s < 2; ++s) {
        int i0 = (b0i + 2 * w + s) * D + 2 * lane;
        float2 o = make_float2(th0[s] * OUT_SCALE, th1[s] * OUT_SCALE);
        *reinterpret_cast<float2*>(&out[i0]) = o;
    }
}

extern "C" void kernel_launch(void* const* d_in, const int* in_sizes, int n_in,
                              void* d_out, int out_size, void* d_ws, size_t ws_size,
                              hipStream_t stream) {
    const float* x     = (const float*)d_in[0];
    const float* w_in  = (const float*)d_in[1];
    const float* b_in  = (const float*)d_in[2];
    const float* w0    = (const float*)d_in[3];
    const float* b0    = (const float*)d_in[4];
    const float* w1    = (const float*)d_in[5];
    const float* b1    = (const float*)d_in[6];
    const float* w_out = (const float*)d_in[7];
    const float* b_out = (const float*)d_in[8];

    short8* pw_in = (short8*)d_ws;                // 1024 slots x 16 B
    short8* pwb0  = pw_in + 1024;                 // 8192 slots
    short8* pwb1  = pwb0 + 8192;
    short8* pwb2  = pwb1 + 8192;
    float* out   = (float*)d_out;

    pack_kernel<<<100, 256, 0, stream>>>(w_in, w0, w1, w_out,
                                         pw_in, pwb0, pwb1, pwb2);

    const float dtf = (float)((59.0 / 30.0) / NSTEP);
    fused_kernel<<<BATCH / 16, 512, 0, stream>>>(
        x, pw_in, b_in, pwb0, b0, pwb1, b1, pwb2, b_out, out, dtf);
}